// Round 10
// baseline (692.708 us; speedup 1.0000x reference)
//
#include <hip/hip_runtime.h>

#define N_NODES 50000
#define N_EDGES 800000

__device__ __forceinline__ float lrelu(float x){ return x > 0.f ? x : 0.2f*x; }
__device__ __forceinline__ float eluf (float x){ return x > 0.f ? x : __expf(x)-1.f; }

// ---------------- CSR build ----------------
__global__ void k_hist(const int* __restrict__ dst, int* __restrict__ cnt){
  int e = blockIdx.x*256 + threadIdx.x;
  if (e < N_EDGES) atomicAdd(&cnt[dst[e]], 1);
}

__global__ void k_scan1(const int* __restrict__ cnt, int* __restrict__ offs, int* __restrict__ bsum){
  __shared__ int tmp[256];
  int tid = threadIdx.x; int i = blockIdx.x*256 + tid;
  int v = (i < N_NODES) ? cnt[i] : 0;
  tmp[tid] = v; __syncthreads();
  for (int d = 1; d < 256; d <<= 1){
    int t = (tid >= d) ? tmp[tid-d] : 0;
    __syncthreads();
    tmp[tid] += t;
    __syncthreads();
  }
  if (i < N_NODES) offs[i] = tmp[tid] - v;          // exclusive within chunk
  if (tid == 255) bsum[blockIdx.x] = tmp[tid];       // chunk total
}

__global__ void k_scan2(int* __restrict__ bsum, int nb){
  __shared__ int tmp[256];
  int tid = threadIdx.x;
  int v = (tid < nb) ? bsum[tid] : 0;
  tmp[tid] = v; __syncthreads();
  for (int d = 1; d < 256; d <<= 1){
    int t = (tid >= d) ? tmp[tid-d] : 0;
    __syncthreads();
    tmp[tid] += t;
    __syncthreads();
  }
  if (tid < nb) bsum[tid] = tmp[tid] - v;            // exclusive chunk offsets
}

__global__ void k_scan3(int* __restrict__ offs, const int* __restrict__ bsum, int* __restrict__ cur){
  int i = blockIdx.x*256 + threadIdx.x;
  if (i < N_NODES){
    int o = offs[i] + bsum[blockIdx.x];
    offs[i] = o; cur[i] = o;
  }
  if (i == 0) offs[N_NODES] = N_EDGES;
}

__global__ void k_scatter(const int* __restrict__ src, const int* __restrict__ dst,
                          int* __restrict__ cur, int* __restrict__ csr_src){
  int e = blockIdx.x*256 + threadIdx.x;
  if (e < N_EDGES){
    int pos = atomicAdd(&cur[dst[e]], 1);
    csr_src[pos] = src[e];
  }
}

// ---------------- GEMM: feat[N,HF] = h[N,128] @ W[128,HF], fused el/er ----------------
// R8's 64x64/4x4 tile (4 blk/CU) + register double-buffering: chunk-1 global
// loads issued BEFORE the chunk-0 K-loop so their latency hides under compute.
template<int HF, int LAYER>
__global__ __launch_bounds__(256) void k_gemm(const float* __restrict__ h,
                                              const float* __restrict__ W,
                                              float* __restrict__ feat,
                                              const float* __restrict__ al,
                                              const float* __restrict__ ar,
                                              float* __restrict__ el,
                                              float* __restrict__ er){
  __shared__ float Wl[64*64];    // [k][j]
  __shared__ float hTl[64*68];   // [k][r], pad 68
  int tid = threadIdx.x;
  int tx = tid & 15, ty = tid >> 4;
  int row0 = blockIdx.x * 64;
  int col0 = blockIdx.y * 64;
  float acc[4][4] = {};

  float4 wreg[4], hreg[4];
  bool rowok[4];
  // ---- issue chunk-0 loads ----
  #pragma unroll
  for (int p = 0; p < 4; ++p){
    int k = p*16 + ty;
    wreg[p] = *(const float4*)&W[(size_t)k*HF + col0 + tx*4];
    int row = row0 + p*16 + ty;
    rowok[p] = row < N_NODES;
    hreg[p] = rowok[p] ? *(const float4*)&h[(size_t)row*128 + tx*4]
                       : make_float4(0.f,0.f,0.f,0.f);
  }
  // ---- store chunk 0 to LDS ----
  #pragma unroll
  for (int p = 0; p < 4; ++p){
    int k = p*16 + ty;
    *(float4*)&Wl[k*64 + tx*4] = wreg[p];
    int r = p*16 + ty;
    hTl[(tx*4+0)*68 + r] = hreg[p].x;
    hTl[(tx*4+1)*68 + r] = hreg[p].y;
    hTl[(tx*4+2)*68 + r] = hreg[p].z;
    hTl[(tx*4+3)*68 + r] = hreg[p].w;
  }
  // ---- issue chunk-1 loads (latency hides under chunk-0 K-loop) ----
  #pragma unroll
  for (int p = 0; p < 4; ++p){
    int k = p*16 + ty;
    wreg[p] = *(const float4*)&W[(size_t)(64 + k)*HF + col0 + tx*4];
    int row = row0 + p*16 + ty;
    hreg[p] = rowok[p] ? *(const float4*)&h[(size_t)row*128 + 64 + tx*4]
                       : make_float4(0.f,0.f,0.f,0.f);
  }
  __syncthreads();
  // ---- K-loop chunk 0 ----
  #pragma unroll 8
  for (int k = 0; k < 64; ++k){
    float4 hv = *(const float4*)&hTl[k*68 + ty*4];
    float4 wv = *(const float4*)&Wl [k*64 + tx*4];
    acc[0][0] += hv.x*wv.x; acc[0][1] += hv.x*wv.y; acc[0][2] += hv.x*wv.z; acc[0][3] += hv.x*wv.w;
    acc[1][0] += hv.y*wv.x; acc[1][1] += hv.y*wv.y; acc[1][2] += hv.y*wv.z; acc[1][3] += hv.y*wv.w;
    acc[2][0] += hv.z*wv.x; acc[2][1] += hv.z*wv.y; acc[2][2] += hv.z*wv.z; acc[2][3] += hv.z*wv.w;
    acc[3][0] += hv.w*wv.x; acc[3][1] += hv.w*wv.y; acc[3][2] += hv.w*wv.z; acc[3][3] += hv.w*wv.w;
  }
  __syncthreads();
  // ---- store chunk 1 to LDS ----
  #pragma unroll
  for (int p = 0; p < 4; ++p){
    int k = p*16 + ty;
    *(float4*)&Wl[k*64 + tx*4] = wreg[p];
    int r = p*16 + ty;
    hTl[(tx*4+0)*68 + r] = hreg[p].x;
    hTl[(tx*4+1)*68 + r] = hreg[p].y;
    hTl[(tx*4+2)*68 + r] = hreg[p].z;
    hTl[(tx*4+3)*68 + r] = hreg[p].w;
  }
  __syncthreads();
  // ---- K-loop chunk 1 ----
  #pragma unroll 8
  for (int k = 0; k < 64; ++k){
    float4 hv = *(const float4*)&hTl[k*68 + ty*4];
    float4 wv = *(const float4*)&Wl [k*64 + tx*4];
    acc[0][0] += hv.x*wv.x; acc[0][1] += hv.x*wv.y; acc[0][2] += hv.x*wv.z; acc[0][3] += hv.x*wv.w;
    acc[1][0] += hv.y*wv.x; acc[1][1] += hv.y*wv.y; acc[1][2] += hv.y*wv.z; acc[1][3] += hv.y*wv.w;
    acc[2][0] += hv.z*wv.x; acc[2][1] += hv.z*wv.y; acc[2][2] += hv.z*wv.z; acc[2][3] += hv.z*wv.w;
    acc[3][0] += hv.w*wv.x; acc[3][1] += hv.w*wv.y; acc[3][2] += hv.w*wv.z; acc[3][3] += hv.w*wv.w;
  }

  #pragma unroll
  for (int i = 0; i < 4; ++i){
    int row = row0 + ty*4 + i;
    if (row < N_NODES)
      *(float4*)&feat[(size_t)row*HF + col0 + tx*4] =
        make_float4(acc[i][0], acc[i][1], acc[i][2], acc[i][3]);
  }
  // ---- fused el/er epilogue ----
  constexpr int F = HF/4;               // head dim
  constexpr int G = (F == 32) ? 8 : 16; // tx-lanes per head
  float4 alv = *(const float4*)&al[col0 + tx*4];
  float4 arv = *(const float4*)&ar[col0 + tx*4];
  int hidx = (col0 + tx*4) / F;
  #pragma unroll
  for (int i = 0; i < 4; ++i){
    float pl = acc[i][0]*alv.x + acc[i][1]*alv.y + acc[i][2]*alv.z + acc[i][3]*alv.w;
    float pr = acc[i][0]*arv.x + acc[i][1]*arv.y + acc[i][2]*arv.z + acc[i][3]*arv.w;
    #pragma unroll
    for (int m = 1; m < G; m <<= 1){
      pl += __shfl_xor(pl, m);
      pr += __shfl_xor(pr, m);
    }
    int row = row0 + ty*4 + i;
    if ((tx & (G-1)) == 0 && row < N_NODES){
      el[row*4 + hidx] = pl;
      er[row*4 + hidx] = pr;
    }
  }
}

// ---------------- fused single-pass softmax + aggregation (1 wave / node) ----------------
// out = (Σ_e ev·feat[src_e]) / (Σ_e ev),  ev = exp(lrelu(el[src]+er[n])).
// ~110-115 µs/layer is the measured chip-wide random row-request-rate floor
// (independent of request size and per-wave MLP — R2/R7/F64 cross-check).
template<int F, bool FINAL, int LAYER>
__global__ __launch_bounds__(256) void k_agg(const int* __restrict__ offs,
        const int* __restrict__ csr_src, const float* __restrict__ el,
        const float* __restrict__ er, const float* __restrict__ feat,
        const float* __restrict__ bias, float* __restrict__ out){
  int lane = threadIdx.x & 63;
  int n = (blockIdx.x*256 + threadIdx.x) >> 6;   // 12500 blocks * 4 waves = 50000 exactly
  if (n >= N_NODES) return;
  int beg = offs[n], end = offs[n+1];
  float4 er4 = ((const float4*)er)[n];

  if (F == 32){
    int half = lane >> 5;        // which edge of the pair
    int l5   = lane & 31;        // feature slot: floats l5*4..l5*4+3 of 128
    int h    = l5 >> 3;
    float er_h = (h==0) ? er4.x : (h==1) ? er4.y : (h==2) ? er4.z : er4.w;
    float a0=0.f, a1=0.f, a2=0.f, a3=0.f, ds=0.f;
    #pragma unroll 2
    for (int base = beg; base < end; base += 2){
      int e = base + half;
      if (e < end){
        int s = csr_src[e];
        float ev = __expf(lrelu(el[s*4 + h] + er_h));
        ds += ev;
        float4 v = *(const float4*)&feat[(size_t)s*128 + l5*4];
        a0 += ev*v.x; a1 += ev*v.y; a2 += ev*v.z; a3 += ev*v.w;
      }
    }
    ds += __shfl_xor(ds, 32);
    a0 += __shfl_xor(a0, 32);
    a1 += __shfl_xor(a1, 32);
    a2 += __shfl_xor(a2, 32);
    a3 += __shfl_xor(a3, 32);
    if (half == 0){
      float rden = 1.f / fmaxf(ds, 1e-9f);
      float4 bv = *(const float4*)&bias[l5*4];
      float4 o;
      o.x = eluf(a0*rden + bv.x);
      o.y = eluf(a1*rden + bv.y);
      o.z = eluf(a2*rden + bv.z);
      o.w = eluf(a3*rden + bv.w);
      *(float4*)&out[(size_t)n*128 + l5*4] = o;
    }
  } else {
    int h = lane >> 4;
    float er_h = (h==0) ? er4.x : (h==1) ? er4.y : (h==2) ? er4.z : er4.w;
    float a0=0.f, a1=0.f, a2=0.f, a3=0.f, ds=0.f;
    #pragma unroll 2
    for (int e = beg; e < end; ++e){
      int s = csr_src[e];
      float ev = __expf(lrelu(el[s*4 + h] + er_h));
      ds += ev;
      float4 v = *(const float4*)&feat[(size_t)s*256 + lane*4];
      a0 += ev*v.x; a1 += ev*v.y; a2 += ev*v.z; a3 += ev*v.w;
    }
    float rden = 1.f / fmaxf(ds, 1e-9f);
    float4 bv = *(const float4*)&bias[lane*4];
    float v0 = a0*rden + bv.x;
    float v1 = a1*rden + bv.y;
    float v2 = a2*rden + bv.z;
    float v3 = a3*rden + bv.w;
    // mean over heads: combine lanes with equal (lane & 15)
    v0 += __shfl_xor(v0, 16); v0 += __shfl_xor(v0, 32);
    v1 += __shfl_xor(v1, 16); v1 += __shfl_xor(v1, 32);
    v2 += __shfl_xor(v2, 16); v2 += __shfl_xor(v2, 32);
    v3 += __shfl_xor(v3, 16); v3 += __shfl_xor(v3, 32);
    if (lane < 16)
      *(float4*)&out[(size_t)n*64 + lane*4] =
        make_float4(v0*0.25f, v1*0.25f, v2*0.25f, v3*0.25f);
  }
}

extern "C" void kernel_launch(void* const* d_in, const int* in_sizes, int n_in,
                              void* d_out, int out_size, void* d_ws, size_t ws_size,
                              hipStream_t stream){
  const float* x   = (const float*)d_in[0];
  const int*   src = (const int*)  d_in[1];
  const int*   dst = (const int*)  d_in[2];
  const float* W[4]  = {(const float*)d_in[3],  (const float*)d_in[7],
                        (const float*)d_in[11], (const float*)d_in[15]};
  const float* al[4] = {(const float*)d_in[4],  (const float*)d_in[8],
                        (const float*)d_in[12], (const float*)d_in[16]};
  const float* ar[4] = {(const float*)d_in[5],  (const float*)d_in[9],
                        (const float*)d_in[13], (const float*)d_in[17]};
  const float* b[4]  = {(const float*)d_in[6],  (const float*)d_in[10],
                        (const float*)d_in[14], (const float*)d_in[18]};

  char* ws = (char*)d_ws;
  float* bufH    = (float*)(ws);                  // 25,600,000
  float* feat    = (float*)(ws + 25600000);       // 51,200,000
  float* el      = (float*)(ws + 76800000);       // 800,000
  float* er      = (float*)(ws + 77600000);       // 800,000
  int*   offs    = (int*)  (ws + 78400000);       // 200,004 (padded)
  int*   cur     = (int*)  (ws + 78600032);       // 200,000
  int*   bsum    = (int*)  (ws + 78800032);       // 1,024
  int*   csr_src = (int*)  (ws + 78801056);       // 3,200,000  (end ~82 MB)

  // ---- CSR build (per call; ws is re-poisoned) ----
  (void)hipMemsetAsync(cur, 0, N_NODES*sizeof(int), stream);
  k_hist   <<<3125, 256, 0, stream>>>(dst, cur);
  k_scan1  <<<196,  256, 0, stream>>>(cur, offs, bsum);
  k_scan2  <<<1,    256, 0, stream>>>(bsum, 196);
  k_scan3  <<<196,  256, 0, stream>>>(offs, bsum, cur);
  k_scatter<<<3125, 256, 0, stream>>>(src, dst, cur, csr_src);

  // ---- layer 1..3 (HF=128, F=32) ----
  k_gemm<128,1><<<dim3(782,2), 256, 0, stream>>>(x, W[0], feat, al[0], ar[0], el, er);
  k_agg<32,false,1><<<12500, 256, 0, stream>>>(offs, csr_src, el, er, feat, b[0], bufH);

  k_gemm<128,2><<<dim3(782,2), 256, 0, stream>>>(bufH, W[1], feat, al[1], ar[1], el, er);
  k_agg<32,false,2><<<12500, 256, 0, stream>>>(offs, csr_src, el, er, feat, b[1], bufH);

  k_gemm<128,3><<<dim3(782,2), 256, 0, stream>>>(bufH, W[2], feat, al[2], ar[2], el, er);
  k_agg<32,false,3><<<12500, 256, 0, stream>>>(offs, csr_src, el, er, feat, b[2], bufH);

  // ---- layer 4 (HF=256, F=64) + head-mean ----
  k_gemm<256,4><<<dim3(782,4), 256, 0, stream>>>(bufH, W[3], feat, al[3], ar[3], el, er);
  k_agg<64,true,4><<<12500, 256, 0, stream>>>(offs, csr_src, el, er, feat, b[3], (float*)d_out);
}

// Round 11
// 666.636 us; speedup vs baseline: 1.0391x; 1.0391x over previous
//
#include <hip/hip_runtime.h>

#define N_NODES 50000
#define N_EDGES 800000

__device__ __forceinline__ float lrelu(float x){ return x > 0.f ? x : 0.2f*x; }
__device__ __forceinline__ float eluf (float x){ return x > 0.f ? x : __expf(x)-1.f; }

// ---------------- CSR build ----------------
__global__ void k_hist(const int* __restrict__ dst, int* __restrict__ cnt){
  int e = blockIdx.x*256 + threadIdx.x;
  if (e < N_EDGES) atomicAdd(&cnt[dst[e]], 1);
}

__global__ void k_scan1(const int* __restrict__ cnt, int* __restrict__ offs, int* __restrict__ bsum){
  __shared__ int tmp[256];
  int tid = threadIdx.x; int i = blockIdx.x*256 + tid;
  int v = (i < N_NODES) ? cnt[i] : 0;
  tmp[tid] = v; __syncthreads();
  for (int d = 1; d < 256; d <<= 1){
    int t = (tid >= d) ? tmp[tid-d] : 0;
    __syncthreads();
    tmp[tid] += t;
    __syncthreads();
  }
  if (i < N_NODES) offs[i] = tmp[tid] - v;          // exclusive within chunk
  if (tid == 255) bsum[blockIdx.x] = tmp[tid];       // chunk total
}

__global__ void k_scan2(int* __restrict__ bsum, int nb){
  __shared__ int tmp[256];
  int tid = threadIdx.x;
  int v = (tid < nb) ? bsum[tid] : 0;
  tmp[tid] = v; __syncthreads();
  for (int d = 1; d < 256; d <<= 1){
    int t = (tid >= d) ? tmp[tid-d] : 0;
    __syncthreads();
    tmp[tid] += t;
    __syncthreads();
  }
  if (tid < nb) bsum[tid] = tmp[tid] - v;            // exclusive chunk offsets
}

__global__ void k_scan3(int* __restrict__ offs, const int* __restrict__ bsum, int* __restrict__ cur){
  int i = blockIdx.x*256 + threadIdx.x;
  if (i < N_NODES){
    int o = offs[i] + bsum[blockIdx.x];
    offs[i] = o; cur[i] = o;
  }
  if (i == 0) offs[N_NODES] = N_EDGES;
}

__global__ void k_scatter(const int* __restrict__ src, const int* __restrict__ dst,
                          int* __restrict__ cur, int* __restrict__ csr_src){
  int e = blockIdx.x*256 + threadIdx.x;
  if (e < N_EDGES){
    int pos = atomicAdd(&cur[dst[e]], 1);
    csr_src[pos] = src[e];
  }
}

// ---------------- GEMM: feat[N,HF] = h[N,128] @ W[128,HF], fused el/er ----------------
// R8's exact tile/mapping (64x64, 4x4/thread, idx-linear h staging). ONE change:
// chunk-1 h loads (same mapping, +64 col) hoisted above the chunk-0 K-loop so
// their HBM/L3 latency (~600cy) hides under ~1500cy of compute. W chunk-1 left
// in place (64 KB table, L2-hot for all blocks).
template<int HF, int LAYER>
__global__ __launch_bounds__(256) void k_gemm(const float* __restrict__ h,
                                              const float* __restrict__ W,
                                              float* __restrict__ feat,
                                              const float* __restrict__ al,
                                              const float* __restrict__ ar,
                                              float* __restrict__ el,
                                              float* __restrict__ er){
  __shared__ float Wl[64*64];    // [k][j]
  __shared__ float hTl[64*68];   // [k][r], pad 68 breaks transpose-store conflicts
  int tid = threadIdx.x;
  int tx = tid & 15, ty = tid >> 4;
  int row0 = blockIdx.x * 64;
  int col0 = blockIdx.y * 64;
  float acc[4][4] = {};

  // ---- chunk-0 staging loads (R8 mapping) ----
  float4 h0[4], w0[4], h1[4];
  #pragma unroll
  for (int p = 0; p < 4; ++p){
    int k = p*16 + ty;
    w0[p] = *(const float4*)&W[(size_t)k*HF + col0 + tx*4];
  }
  #pragma unroll
  for (int p = 0; p < 4; ++p){
    int idx = (p*256 + tid)*4;              // 0..4095
    int r = idx >> 6, c = idx & 63;
    int row = row0 + r;
    h0[p] = (row < N_NODES) ? *(const float4*)&h[(size_t)row*128 + c]
                            : make_float4(0.f,0.f,0.f,0.f);
  }
  // ---- chunk-1 h loads issued NOW (latency hides under chunk-0 K-loop) ----
  #pragma unroll
  for (int p = 0; p < 4; ++p){
    int idx = (p*256 + tid)*4;
    int r = idx >> 6, c = idx & 63;
    int row = row0 + r;
    h1[p] = (row < N_NODES) ? *(const float4*)&h[(size_t)row*128 + 64 + c]
                            : make_float4(0.f,0.f,0.f,0.f);
  }
  // ---- store chunk 0 (R8's exact LDS pattern) ----
  #pragma unroll
  for (int p = 0; p < 4; ++p){
    int k = p*16 + ty;
    *(float4*)&Wl[k*64 + tx*4] = w0[p];
  }
  #pragma unroll
  for (int p = 0; p < 4; ++p){
    int idx = (p*256 + tid)*4;
    int r = idx >> 6, c = idx & 63;
    hTl[(c+0)*68 + r] = h0[p].x;
    hTl[(c+1)*68 + r] = h0[p].y;
    hTl[(c+2)*68 + r] = h0[p].z;
    hTl[(c+3)*68 + r] = h0[p].w;
  }
  __syncthreads();
  // ---- K-loop chunk 0 ----
  #pragma unroll 8
  for (int k = 0; k < 64; ++k){
    float4 hv = *(const float4*)&hTl[k*68 + ty*4];
    float4 wv = *(const float4*)&Wl [k*64 + tx*4];
    acc[0][0] += hv.x*wv.x; acc[0][1] += hv.x*wv.y; acc[0][2] += hv.x*wv.z; acc[0][3] += hv.x*wv.w;
    acc[1][0] += hv.y*wv.x; acc[1][1] += hv.y*wv.y; acc[1][2] += hv.y*wv.z; acc[1][3] += hv.y*wv.w;
    acc[2][0] += hv.z*wv.x; acc[2][1] += hv.z*wv.y; acc[2][2] += hv.z*wv.z; acc[2][3] += hv.z*wv.w;
    acc[3][0] += hv.w*wv.x; acc[3][1] += hv.w*wv.y; acc[3][2] += hv.w*wv.z; acc[3][3] += hv.w*wv.w;
  }
  __syncthreads();
  // ---- stage chunk 1: W fresh (L2-hot), h from registers ----
  #pragma unroll
  for (int p = 0; p < 4; ++p){
    int k = p*16 + ty;
    float4 wv = *(const float4*)&W[(size_t)(64 + k)*HF + col0 + tx*4];
    *(float4*)&Wl[k*64 + tx*4] = wv;
  }
  #pragma unroll
  for (int p = 0; p < 4; ++p){
    int idx = (p*256 + tid)*4;
    int r = idx >> 6, c = idx & 63;
    hTl[(c+0)*68 + r] = h1[p].x;
    hTl[(c+1)*68 + r] = h1[p].y;
    hTl[(c+2)*68 + r] = h1[p].z;
    hTl[(c+3)*68 + r] = h1[p].w;
  }
  __syncthreads();
  // ---- K-loop chunk 1 ----
  #pragma unroll 8
  for (int k = 0; k < 64; ++k){
    float4 hv = *(const float4*)&hTl[k*68 + ty*4];
    float4 wv = *(const float4*)&Wl [k*64 + tx*4];
    acc[0][0] += hv.x*wv.x; acc[0][1] += hv.x*wv.y; acc[0][2] += hv.x*wv.z; acc[0][3] += hv.x*wv.w;
    acc[1][0] += hv.y*wv.x; acc[1][1] += hv.y*wv.y; acc[1][2] += hv.y*wv.z; acc[1][3] += hv.y*wv.w;
    acc[2][0] += hv.z*wv.x; acc[2][1] += hv.z*wv.y; acc[2][2] += hv.z*wv.z; acc[2][3] += hv.z*wv.w;
    acc[3][0] += hv.w*wv.x; acc[3][1] += hv.w*wv.y; acc[3][2] += hv.w*wv.z; acc[3][3] += hv.w*wv.w;
  }

  #pragma unroll
  for (int i = 0; i < 4; ++i){
    int row = row0 + ty*4 + i;
    if (row < N_NODES)
      *(float4*)&feat[(size_t)row*HF + col0 + tx*4] =
        make_float4(acc[i][0], acc[i][1], acc[i][2], acc[i][3]);
  }
  // ---- fused el/er epilogue ----
  constexpr int F = HF/4;               // head dim
  constexpr int G = (F == 32) ? 8 : 16; // tx-lanes per head
  float4 alv = *(const float4*)&al[col0 + tx*4];
  float4 arv = *(const float4*)&ar[col0 + tx*4];
  int hidx = (col0 + tx*4) / F;
  #pragma unroll
  for (int i = 0; i < 4; ++i){
    float pl = acc[i][0]*alv.x + acc[i][1]*alv.y + acc[i][2]*alv.z + acc[i][3]*alv.w;
    float pr = acc[i][0]*arv.x + acc[i][1]*arv.y + acc[i][2]*arv.z + acc[i][3]*arv.w;
    #pragma unroll
    for (int m = 1; m < G; m <<= 1){
      pl += __shfl_xor(pl, m);
      pr += __shfl_xor(pr, m);
    }
    int row = row0 + ty*4 + i;
    if ((tx & (G-1)) == 0 && row < N_NODES){
      el[row*4 + hidx] = pl;
      er[row*4 + hidx] = pr;
    }
  }
}

// ---------------- fused single-pass softmax + aggregation (1 wave / node) ----------------
// out = (Σ_e ev·feat[src_e]) / (Σ_e ev),  ev = exp(lrelu(el[src]+er[n])).
// ~115 µs/layer is the measured chip-wide random row-request-rate floor
// (independent of request size and per-wave MLP — R2/R7/F64 cross-check).
template<int F, bool FINAL, int LAYER>
__global__ __launch_bounds__(256) void k_agg(const int* __restrict__ offs,
        const int* __restrict__ csr_src, const float* __restrict__ el,
        const float* __restrict__ er, const float* __restrict__ feat,
        const float* __restrict__ bias, float* __restrict__ out){
  int lane = threadIdx.x & 63;
  int n = (blockIdx.x*256 + threadIdx.x) >> 6;   // 12500 blocks * 4 waves = 50000 exactly
  if (n >= N_NODES) return;
  int beg = offs[n], end = offs[n+1];
  float4 er4 = ((const float4*)er)[n];

  if (F == 32){
    int half = lane >> 5;        // which edge of the pair
    int l5   = lane & 31;        // feature slot: floats l5*4..l5*4+3 of 128
    int h    = l5 >> 3;
    float er_h = (h==0) ? er4.x : (h==1) ? er4.y : (h==2) ? er4.z : er4.w;
    float a0=0.f, a1=0.f, a2=0.f, a3=0.f, ds=0.f;
    #pragma unroll 2
    for (int base = beg; base < end; base += 2){
      int e = base + half;
      if (e < end){
        int s = csr_src[e];
        float ev = __expf(lrelu(el[s*4 + h] + er_h));
        ds += ev;
        float4 v = *(const float4*)&feat[(size_t)s*128 + l5*4];
        a0 += ev*v.x; a1 += ev*v.y; a2 += ev*v.z; a3 += ev*v.w;
      }
    }
    ds += __shfl_xor(ds, 32);
    a0 += __shfl_xor(a0, 32);
    a1 += __shfl_xor(a1, 32);
    a2 += __shfl_xor(a2, 32);
    a3 += __shfl_xor(a3, 32);
    if (half == 0){
      float rden = 1.f / fmaxf(ds, 1e-9f);
      float4 bv = *(const float4*)&bias[l5*4];
      float4 o;
      o.x = eluf(a0*rden + bv.x);
      o.y = eluf(a1*rden + bv.y);
      o.z = eluf(a2*rden + bv.z);
      o.w = eluf(a3*rden + bv.w);
      *(float4*)&out[(size_t)n*128 + l5*4] = o;
    }
  } else {
    int h = lane >> 4;
    float er_h = (h==0) ? er4.x : (h==1) ? er4.y : (h==2) ? er4.z : er4.w;
    float a0=0.f, a1=0.f, a2=0.f, a3=0.f, ds=0.f;
    #pragma unroll 2
    for (int e = beg; e < end; ++e){
      int s = csr_src[e];
      float ev = __expf(lrelu(el[s*4 + h] + er_h));
      ds += ev;
      float4 v = *(const float4*)&feat[(size_t)s*256 + lane*4];
      a0 += ev*v.x; a1 += ev*v.y; a2 += ev*v.z; a3 += ev*v.w;
    }
    float rden = 1.f / fmaxf(ds, 1e-9f);
    float4 bv = *(const float4*)&bias[lane*4];
    float v0 = a0*rden + bv.x;
    float v1 = a1*rden + bv.y;
    float v2 = a2*rden + bv.z;
    float v3 = a3*rden + bv.w;
    // mean over heads: combine lanes with equal (lane & 15)
    v0 += __shfl_xor(v0, 16); v0 += __shfl_xor(v0, 32);
    v1 += __shfl_xor(v1, 16); v1 += __shfl_xor(v1, 32);
    v2 += __shfl_xor(v2, 16); v2 += __shfl_xor(v2, 32);
    v3 += __shfl_xor(v3, 16); v3 += __shfl_xor(v3, 32);
    if (lane < 16)
      *(float4*)&out[(size_t)n*64 + lane*4] =
        make_float4(v0*0.25f, v1*0.25f, v2*0.25f, v3*0.25f);
  }
}

extern "C" void kernel_launch(void* const* d_in, const int* in_sizes, int n_in,
                              void* d_out, int out_size, void* d_ws, size_t ws_size,
                              hipStream_t stream){
  const float* x   = (const float*)d_in[0];
  const int*   src = (const int*)  d_in[1];
  const int*   dst = (const int*)  d_in[2];
  const float* W[4]  = {(const float*)d_in[3],  (const float*)d_in[7],
                        (const float*)d_in[11], (const float*)d_in[15]};
  const float* al[4] = {(const float*)d_in[4],  (const float*)d_in[8],
                        (const float*)d_in[12], (const float*)d_in[16]};
  const float* ar[4] = {(const float*)d_in[5],  (const float*)d_in[9],
                        (const float*)d_in[13], (const float*)d_in[17]};
  const float* b[4]  = {(const float*)d_in[6],  (const float*)d_in[10],
                        (const float*)d_in[14], (const float*)d_in[18]};

  char* ws = (char*)d_ws;
  float* bufH    = (float*)(ws);                  // 25,600,000
  float* feat    = (float*)(ws + 25600000);       // 51,200,000
  float* el      = (float*)(ws + 76800000);       // 800,000
  float* er      = (float*)(ws + 77600000);       // 800,000
  int*   offs    = (int*)  (ws + 78400000);       // 200,004 (padded)
  int*   cur     = (int*)  (ws + 78600032);       // 200,000
  int*   bsum    = (int*)  (ws + 78800032);       // 1,024
  int*   csr_src = (int*)  (ws + 78801056);       // 3,200,000  (end ~82 MB)

  // ---- CSR build (per call; ws is re-poisoned) ----
  (void)hipMemsetAsync(cur, 0, N_NODES*sizeof(int), stream);
  k_hist   <<<3125, 256, 0, stream>>>(dst, cur);
  k_scan1  <<<196,  256, 0, stream>>>(cur, offs, bsum);
  k_scan2  <<<1,    256, 0, stream>>>(bsum, 196);
  k_scan3  <<<196,  256, 0, stream>>>(offs, bsum, cur);
  k_scatter<<<3125, 256, 0, stream>>>(src, dst, cur, csr_src);

  // ---- layer 1..3 (HF=128, F=32) ----
  k_gemm<128,1><<<dim3(782,2), 256, 0, stream>>>(x, W[0], feat, al[0], ar[0], el, er);
  k_agg<32,false,1><<<12500, 256, 0, stream>>>(offs, csr_src, el, er, feat, b[0], bufH);

  k_gemm<128,2><<<dim3(782,2), 256, 0, stream>>>(bufH, W[1], feat, al[1], ar[1], el, er);
  k_agg<32,false,2><<<12500, 256, 0, stream>>>(offs, csr_src, el, er, feat, b[1], bufH);

  k_gemm<128,3><<<dim3(782,2), 256, 0, stream>>>(bufH, W[2], feat, al[2], ar[2], el, er);
  k_agg<32,false,3><<<12500, 256, 0, stream>>>(offs, csr_src, el, er, feat, b[2], bufH);

  // ---- layer 4 (HF=256, F=64) + head-mean ----
  k_gemm<256,4><<<dim3(782,4), 256, 0, stream>>>(bufH, W[3], feat, al[3], ar[3], el, er);
  k_agg<64,true,4><<<12500, 256, 0, stream>>>(offs, csr_src, el, er, feat, b[3], (float*)d_out);
}

// Round 12
// 660.503 us; speedup vs baseline: 1.0488x; 1.0093x over previous
//
#include <hip/hip_runtime.h>

#define N_NODES 50000
#define N_EDGES 800000

__device__ __forceinline__ float lrelu(float x){ return x > 0.f ? x : 0.2f*x; }
__device__ __forceinline__ float eluf (float x){ return x > 0.f ? x : __expf(x)-1.f; }

// ---------------- CSR build ----------------
__global__ void k_hist(const int* __restrict__ dst, int* __restrict__ cnt){
  int e = blockIdx.x*256 + threadIdx.x;
  if (e < N_EDGES) atomicAdd(&cnt[dst[e]], 1);
}

__global__ void k_scan1(const int* __restrict__ cnt, int* __restrict__ offs, int* __restrict__ bsum){
  __shared__ int tmp[256];
  int tid = threadIdx.x; int i = blockIdx.x*256 + tid;
  int v = (i < N_NODES) ? cnt[i] : 0;
  tmp[tid] = v; __syncthreads();
  for (int d = 1; d < 256; d <<= 1){
    int t = (tid >= d) ? tmp[tid-d] : 0;
    __syncthreads();
    tmp[tid] += t;
    __syncthreads();
  }
  if (i < N_NODES) offs[i] = tmp[tid] - v;          // exclusive within chunk
  if (tid == 255) bsum[blockIdx.x] = tmp[tid];       // chunk total
}

__global__ void k_scan2(int* __restrict__ bsum, int nb){
  __shared__ int tmp[256];
  int tid = threadIdx.x;
  int v = (tid < nb) ? bsum[tid] : 0;
  tmp[tid] = v; __syncthreads();
  for (int d = 1; d < 256; d <<= 1){
    int t = (tid >= d) ? tmp[tid-d] : 0;
    __syncthreads();
    tmp[tid] += t;
    __syncthreads();
  }
  if (tid < nb) bsum[tid] = tmp[tid] - v;            // exclusive chunk offsets
}

__global__ void k_scan3(int* __restrict__ offs, const int* __restrict__ bsum, int* __restrict__ cur){
  int i = blockIdx.x*256 + threadIdx.x;
  if (i < N_NODES){
    int o = offs[i] + bsum[blockIdx.x];
    offs[i] = o; cur[i] = o;
  }
  if (i == 0) offs[N_NODES] = N_EDGES;
}

__global__ void k_scatter(const int* __restrict__ src, const int* __restrict__ dst,
                          int* __restrict__ cur, int* __restrict__ csr_src){
  int e = blockIdx.x*256 + threadIdx.x;
  if (e < N_EDGES){
    int pos = atomicAdd(&cur[dst[e]], 1);
    csr_src[pos] = src[e];
  }
}

// ---------------- GEMM: feat[N,HF] = h[N,128] @ W[128,HF], fused el/er ----------------
// 64x64 tile, 4x4/thread, idx-linear h staging (wave reads 4KB contiguous),
// pad-68 transpose store. Measured best across R8-R11 variants (bigger tile,
// reg-dbuf, prefetch all neutral-or-worse: wave-level overlap at 4 blk/CU
// already hides staging latency).
template<int HF, int LAYER>
__global__ __launch_bounds__(256) void k_gemm(const float* __restrict__ h,
                                              const float* __restrict__ W,
                                              float* __restrict__ feat,
                                              const float* __restrict__ al,
                                              const float* __restrict__ ar,
                                              float* __restrict__ el,
                                              float* __restrict__ er){
  __shared__ float Wl[64*64];    // [k][j]
  __shared__ float hTl[64*68];   // [k][r], pad 68 breaks transpose-store conflicts
  int tid = threadIdx.x;
  int tx = tid & 15, ty = tid >> 4;
  int row0 = blockIdx.x * 64;
  int col0 = blockIdx.y * 64;
  float acc[4][4] = {};
  for (int kc = 0; kc < 2; ++kc){
    #pragma unroll
    for (int p = 0; p < 4; ++p){              // stage W chunk [64k x 64j]
      int k = p*16 + ty;
      float4 wv = *(const float4*)&W[(size_t)(kc*64 + k)*HF + col0 + tx*4];
      *(float4*)&Wl[k*64 + tx*4] = wv;
    }
    #pragma unroll
    for (int p = 0; p < 4; ++p){              // stage h chunk transposed
      int idx = (p*256 + tid)*4;              // 0..4095
      int r = idx >> 6, c = idx & 63;
      float4 hv = make_float4(0.f,0.f,0.f,0.f);
      int row = row0 + r;
      if (row < N_NODES) hv = *(const float4*)&h[(size_t)row*128 + kc*64 + c];
      hTl[(c+0)*68 + r] = hv.x;
      hTl[(c+1)*68 + r] = hv.y;
      hTl[(c+2)*68 + r] = hv.z;
      hTl[(c+3)*68 + r] = hv.w;
    }
    __syncthreads();
    #pragma unroll 8
    for (int k = 0; k < 64; ++k){
      float4 hv = *(const float4*)&hTl[k*68 + ty*4];
      float4 wv = *(const float4*)&Wl [k*64 + tx*4];
      acc[0][0] += hv.x*wv.x; acc[0][1] += hv.x*wv.y; acc[0][2] += hv.x*wv.z; acc[0][3] += hv.x*wv.w;
      acc[1][0] += hv.y*wv.x; acc[1][1] += hv.y*wv.y; acc[1][2] += hv.y*wv.z; acc[1][3] += hv.y*wv.w;
      acc[2][0] += hv.z*wv.x; acc[2][1] += hv.z*wv.y; acc[2][2] += hv.z*wv.z; acc[2][3] += hv.z*wv.w;
      acc[3][0] += hv.w*wv.x; acc[3][1] += hv.w*wv.y; acc[3][2] += hv.w*wv.z; acc[3][3] += hv.w*wv.w;
    }
    __syncthreads();
  }
  #pragma unroll
  for (int i = 0; i < 4; ++i){
    int row = row0 + ty*4 + i;
    if (row < N_NODES)
      *(float4*)&feat[(size_t)row*HF + col0 + tx*4] =
        make_float4(acc[i][0], acc[i][1], acc[i][2], acc[i][3]);
  }
  // ---- fused el/er epilogue ----
  constexpr int F = HF/4;               // head dim
  constexpr int G = (F == 32) ? 8 : 16; // tx-lanes per head
  float4 alv = *(const float4*)&al[col0 + tx*4];
  float4 arv = *(const float4*)&ar[col0 + tx*4];
  int hidx = (col0 + tx*4) / F;
  #pragma unroll
  for (int i = 0; i < 4; ++i){
    float pl = acc[i][0]*alv.x + acc[i][1]*alv.y + acc[i][2]*alv.z + acc[i][3]*alv.w;
    float pr = acc[i][0]*arv.x + acc[i][1]*arv.y + acc[i][2]*arv.z + acc[i][3]*arv.w;
    #pragma unroll
    for (int m = 1; m < G; m <<= 1){
      pl += __shfl_xor(pl, m);
      pr += __shfl_xor(pr, m);
    }
    int row = row0 + ty*4 + i;
    if ((tx & (G-1)) == 0 && row < N_NODES){
      el[row*4 + hidx] = pl;
      er[row*4 + hidx] = pr;
    }
  }
}

// ---------------- fused single-pass softmax + aggregation (1 wave / node) ----------------
// out = (Σ_e ev·feat[src_e]) / (Σ_e ev),  ev = exp(lrelu(el[src]+er[n])).
// ~115 µs/layer is the measured chip-wide random row-request-rate floor
// (~7e9 segment-requests/s), invariant under request size (512B vs 1KB),
// forced per-wave MLP (asm gather4, R7), and pass structure (R2/R8).
template<int F, bool FINAL, int LAYER>
__global__ __launch_bounds__(256) void k_agg(const int* __restrict__ offs,
        const int* __restrict__ csr_src, const float* __restrict__ el,
        const float* __restrict__ er, const float* __restrict__ feat,
        const float* __restrict__ bias, float* __restrict__ out){
  int lane = threadIdx.x & 63;
  int n = (blockIdx.x*256 + threadIdx.x) >> 6;   // 12500 blocks * 4 waves = 50000 exactly
  if (n >= N_NODES) return;
  int beg = offs[n], end = offs[n+1];
  float4 er4 = ((const float4*)er)[n];

  if (F == 32){
    int half = lane >> 5;        // which edge of the pair
    int l5   = lane & 31;        // feature slot: floats l5*4..l5*4+3 of 128
    int h    = l5 >> 3;
    float er_h = (h==0) ? er4.x : (h==1) ? er4.y : (h==2) ? er4.z : er4.w;
    float a0=0.f, a1=0.f, a2=0.f, a3=0.f, ds=0.f;
    #pragma unroll 2
    for (int base = beg; base < end; base += 2){
      int e = base + half;
      if (e < end){
        int s = csr_src[e];
        float ev = __expf(lrelu(el[s*4 + h] + er_h));
        ds += ev;
        float4 v = *(const float4*)&feat[(size_t)s*128 + l5*4];
        a0 += ev*v.x; a1 += ev*v.y; a2 += ev*v.z; a3 += ev*v.w;
      }
    }
    ds += __shfl_xor(ds, 32);
    a0 += __shfl_xor(a0, 32);
    a1 += __shfl_xor(a1, 32);
    a2 += __shfl_xor(a2, 32);
    a3 += __shfl_xor(a3, 32);
    if (half == 0){
      float rden = 1.f / fmaxf(ds, 1e-9f);
      float4 bv = *(const float4*)&bias[l5*4];
      float4 o;
      o.x = eluf(a0*rden + bv.x);
      o.y = eluf(a1*rden + bv.y);
      o.z = eluf(a2*rden + bv.z);
      o.w = eluf(a3*rden + bv.w);
      *(float4*)&out[(size_t)n*128 + l5*4] = o;
    }
  } else {
    int h = lane >> 4;
    float er_h = (h==0) ? er4.x : (h==1) ? er4.y : (h==2) ? er4.z : er4.w;
    float a0=0.f, a1=0.f, a2=0.f, a3=0.f, ds=0.f;
    #pragma unroll 2
    for (int e = beg; e < end; ++e){
      int s = csr_src[e];
      float ev = __expf(lrelu(el[s*4 + h] + er_h));
      ds += ev;
      float4 v = *(const float4*)&feat[(size_t)s*256 + lane*4];
      a0 += ev*v.x; a1 += ev*v.y; a2 += ev*v.z; a3 += ev*v.w;
    }
    float rden = 1.f / fmaxf(ds, 1e-9f);
    float4 bv = *(const float4*)&bias[lane*4];
    float v0 = a0*rden + bv.x;
    float v1 = a1*rden + bv.y;
    float v2 = a2*rden + bv.z;
    float v3 = a3*rden + bv.w;
    // mean over heads: combine lanes with equal (lane & 15)
    v0 += __shfl_xor(v0, 16); v0 += __shfl_xor(v0, 32);
    v1 += __shfl_xor(v1, 16); v1 += __shfl_xor(v1, 32);
    v2 += __shfl_xor(v2, 16); v2 += __shfl_xor(v2, 32);
    v3 += __shfl_xor(v3, 16); v3 += __shfl_xor(v3, 32);
    if (lane < 16)
      *(float4*)&out[(size_t)n*64 + lane*4] =
        make_float4(v0*0.25f, v1*0.25f, v2*0.25f, v3*0.25f);
  }
}

extern "C" void kernel_launch(void* const* d_in, const int* in_sizes, int n_in,
                              void* d_out, int out_size, void* d_ws, size_t ws_size,
                              hipStream_t stream){
  const float* x   = (const float*)d_in[0];
  const int*   src = (const int*)  d_in[1];
  const int*   dst = (const int*)  d_in[2];
  const float* W[4]  = {(const float*)d_in[3],  (const float*)d_in[7],
                        (const float*)d_in[11], (const float*)d_in[15]};
  const float* al[4] = {(const float*)d_in[4],  (const float*)d_in[8],
                        (const float*)d_in[12], (const float*)d_in[16]};
  const float* ar[4] = {(const float*)d_in[5],  (const float*)d_in[9],
                        (const float*)d_in[13], (const float*)d_in[17]};
  const float* b[4]  = {(const float*)d_in[6],  (const float*)d_in[10],
                        (const float*)d_in[14], (const float*)d_in[18]};

  char* ws = (char*)d_ws;
  float* bufH    = (float*)(ws);                  // 25,600,000
  float* feat    = (float*)(ws + 25600000);       // 51,200,000
  float* el      = (float*)(ws + 76800000);       // 800,000
  float* er      = (float*)(ws + 77600000);       // 800,000
  int*   offs    = (int*)  (ws + 78400000);       // 200,004 (padded)
  int*   cur     = (int*)  (ws + 78600032);       // 200,000
  int*   bsum    = (int*)  (ws + 78800032);       // 1,024
  int*   csr_src = (int*)  (ws + 78801056);       // 3,200,000  (end ~82 MB)

  // ---- CSR build (per call; ws is re-poisoned) ----
  (void)hipMemsetAsync(cur, 0, N_NODES*sizeof(int), stream);
  k_hist   <<<3125, 256, 0, stream>>>(dst, cur);
  k_scan1  <<<196,  256, 0, stream>>>(cur, offs, bsum);
  k_scan2  <<<1,    256, 0, stream>>>(bsum, 196);
  k_scan3  <<<196,  256, 0, stream>>>(offs, bsum, cur);
  k_scatter<<<3125, 256, 0, stream>>>(src, dst, cur, csr_src);

  // ---- layer 1..3 (HF=128, F=32) ----
  k_gemm<128,1><<<dim3(782,2), 256, 0, stream>>>(x, W[0], feat, al[0], ar[0], el, er);
  k_agg<32,false,1><<<12500, 256, 0, stream>>>(offs, csr_src, el, er, feat, b[0], bufH);

  k_gemm<128,2><<<dim3(782,2), 256, 0, stream>>>(bufH, W[1], feat, al[1], ar[1], el, er);
  k_agg<32,false,2><<<12500, 256, 0, stream>>>(offs, csr_src, el, er, feat, b[1], bufH);

  k_gemm<128,3><<<dim3(782,2), 256, 0, stream>>>(bufH, W[2], feat, al[2], ar[2], el, er);
  k_agg<32,false,3><<<12500, 256, 0, stream>>>(offs, csr_src, el, er, feat, b[2], bufH);

  // ---- layer 4 (HF=256, F=64) + head-mean ----
  k_gemm<256,4><<<dim3(782,4), 256, 0, stream>>>(bufH, W[3], feat, al[3], ar[3], el, er);
  k_agg<64,true,4><<<12500, 256, 0, stream>>>(offs, csr_src, el, er, feat, b[3], (float*)d_out);
}